// Round 1
// 3363.861 us; speedup vs baseline: 1.2336x; 1.2336x over previous
//
#include <hip/hip_runtime.h>
#include <stdint.h>

#define N_USERS 200000
#define N_ITEMS 200000
#define NTOT    400000
#define DD      64
#define NNZ     12800000
#define NB      391          // ceil(400000 / 1024) coarse buckets (row >> 10)

typedef unsigned short u16;
typedef float f4 __attribute__((ext_vector_type(4)));
typedef short s8 __attribute__((ext_vector_type(8)));   // 8 bf16 in 4 VGPRs

__device__ __forceinline__ float bf2f(u16 u){
  union { unsigned int i; float f; } x; x.i = ((unsigned int)u) << 16; return x.f;
}
__device__ __forceinline__ u16 f2bf(float f){
  unsigned int i = __float_as_uint(f);
  unsigned int r = (i + 0x7FFFu + ((i >> 16) & 1u)) >> 16;
  return (u16)r;
}

// ---------- init: ego(bf16) = concat(user,item); out[:,0:64] = fp32 copy ----------
__global__ __launch_bounds__(256) void k_init(const float* __restrict__ ue,
                                              const float* __restrict__ ie,
                                              u16* __restrict__ ego,
                                              float* __restrict__ out){
  int t = blockIdx.x * 256 + threadIdx.x;          // 0 .. NTOT*64
  float v = (t < N_USERS * DD) ? ue[t] : ie[t - N_USERS * DD];
  ego[t] = f2bf(v);
  int row = t >> 6, col = t & 63;
  out[row * 256 + col] = v;
}

// ---------- coarse histogram over 391 buckets, LDS-aggregated ----------
__global__ __launch_bounds__(256) void k_chist(const int* __restrict__ rows,
                                               int* __restrict__ cnt_b){
  __shared__ int h[NB];
  for (int i = threadIdx.x; i < NB; i += 256) h[i] = 0;
  __syncthreads();
  for (int e = blockIdx.x * 256 + threadIdx.x; e < NNZ; e += gridDim.x * 256)
    atomicAdd(&h[rows[e] >> 10], 1);
  __syncthreads();
  for (int i = threadIdx.x; i < NB; i += 256)
    if (h[i]) atomicAdd(&cnt_b[i], h[i]);
}

// ---------- scan 391 bucket counts (single block); also off[NTOT]=NNZ ----------
__global__ __launch_bounds__(512) void k_cscan(const int* __restrict__ cnt_b,
                                               int* __restrict__ cstart,
                                               int* __restrict__ ccursor,
                                               int* __restrict__ off){
  __shared__ int s[512];
  int t = threadIdx.x;
  int v = (t < NB) ? cnt_b[t] : 0;
  s[t] = v;
  __syncthreads();
  #pragma unroll
  for (int d = 1; d < 512; d <<= 1){
    int u = (t >= d) ? s[t - d] : 0;
    __syncthreads();
    s[t] += u;
    __syncthreads();
  }
  int excl = s[t] - v;
  if (t < NB){ cstart[t] = excl; ccursor[t] = excl; }
  if (t == NB - 1) cstart[NB] = excl + v;       // == NNZ
  if (t == 0) off[NTOT] = NNZ;
}

// ---------- coarse multisplit: edges -> bucket-grouped tmp (8B packed) ----------
// tile = 4096 edges per 512-thread block; grid = NNZ/4096 = 3125
__global__ __launch_bounds__(512) void k_part(const int* __restrict__ rows,
                                              const int* __restrict__ cols,
                                              const float* __restrict__ vals,
                                              int* __restrict__ ccursor,
                                              uint2* __restrict__ tmp){
  __shared__ int h[512];
  int tid = threadIdx.x;
  int base = blockIdx.x * 4096;
  h[tid] = 0;
  __syncthreads();
  int myb[8]; int myrank[8]; unsigned mykey[8], myval[8];
  #pragma unroll
  for (int k = 0; k < 8; k++){
    int e = base + k * 512 + tid;
    int r = rows[e];
    unsigned c = (unsigned)cols[e];                 // < 2^19
    float v = vals[e];
    int b = r >> 10;
    myb[k] = b;
    mykey[k] = ((unsigned)(r & 1023) << 19) | c;    // 10b localrow | 19b col
    myval[k] = __float_as_uint(v);
    myrank[k] = atomicAdd(&h[b], 1);                // tile-local rank in bucket
  }
  __syncthreads();
  int cnt = h[tid];
  int gb = 0;
  if (tid < NB && cnt > 0) gb = atomicAdd(&ccursor[tid], cnt);   // chunk reservation
  __syncthreads();
  h[tid] = gb;
  __syncthreads();
  #pragma unroll
  for (int k = 0; k < 8; k++)
    tmp[h[myb[k]] + myrank[k]] = make_uint2(mykey[k], myval[k]);
}

// ---------- fine pass: one block per bucket; builds CSR off[] + sorted edges ----------
__global__ __launch_bounds__(256) void k_fine(const int* __restrict__ cstart,
                                              const uint2* __restrict__ tmp,
                                              int* __restrict__ off,
                                              uint2* __restrict__ edges){
  __shared__ int rh[1024];
  __shared__ int sc[256];
  int b = blockIdx.x, tid = threadIdx.x;
  int s = cstart[b], e = cstart[b + 1];
  for (int i = tid; i < 1024; i += 256) rh[i] = 0;
  __syncthreads();
  // pass 1: per-row histogram (LDS atomics)
  for (int i = s + tid; i < e; i += 256)
    atomicAdd(&rh[tmp[i].x >> 19], 1);
  __syncthreads();
  // exclusive scan of 1024 bins with 256 threads (4 bins each)
  int base4 = tid * 4;
  int a0 = rh[base4], a1 = rh[base4 + 1], a2 = rh[base4 + 2], a3 = rh[base4 + 3];
  int tsum = a0 + a1 + a2 + a3;
  sc[tid] = tsum;
  __syncthreads();
  #pragma unroll
  for (int d = 1; d < 256; d <<= 1){
    int u = (tid >= d) ? sc[tid - d] : 0;
    __syncthreads();
    sc[tid] += u;
    __syncthreads();
  }
  int excl = sc[tid] - tsum;
  int r0 = excl, r1 = excl + a0, r2 = excl + a0 + a1, r3 = excl + a0 + a1 + a2;
  rh[base4] = r0; rh[base4 + 1] = r1; rh[base4 + 2] = r2; rh[base4 + 3] = r3;
  // emit global CSR offsets for this bucket's rows
  int rows_in = min(1024, NTOT - b * 1024);
  if (base4     < rows_in) off[b * 1024 + base4]     = s + r0;
  if (base4 + 1 < rows_in) off[b * 1024 + base4 + 1] = s + r1;
  if (base4 + 2 < rows_in) off[b * 1024 + base4 + 2] = s + r2;
  if (base4 + 3 < rows_in) off[b * 1024 + base4 + 3] = s + r3;
  __syncthreads();
  // pass 2: scatter within bucket region (all writes land in own XCD L2)
  for (int i = s + tid; i < e; i += 256){
    uint2 ed = tmp[i];
    unsigned k = ed.x >> 19;
    int pos = atomicAdd(&rh[k], 1);
    edges[s + pos] = make_uint2(ed.x & 0x7FFFFu, ed.y);
  }
}

// ---------- pull-SpMM: one wave per row, lane = column d ----------
__global__ __launch_bounds__(256) void k_spmm(const int* __restrict__ off,
                                              const uint2* __restrict__ edges,
                                              const u16* __restrict__ ego,
                                              u16* __restrict__ side){
  int wid  = (blockIdx.x * 256 + threadIdx.x) >> 6;   // row
  int lane = threadIdx.x & 63;
  int s0 = off[wid], s1 = off[wid + 1];
  float acc = 0.0f;
  int e = s0;
  for (; e + 1 < s1; e += 2){
    uint2 e0 = edges[e];
    uint2 e1 = edges[e + 1];
    float x0 = bf2f(ego[(unsigned)e0.x * 64u + lane]);
    float x1 = bf2f(ego[(unsigned)e1.x * 64u + lane]);
    acc += __uint_as_float(e0.y) * x0;
    acc += __uint_as_float(e1.y) * x1;
  }
  if (e < s1){
    uint2 e0 = edges[e];
    acc += __uint_as_float(e0.y) * bf2f(ego[(unsigned)e0.x * 64u + lane]);
  }
  side[wid * 64 + lane] = f2bf(acc);
}

// ---------- fused layer: GC + Bi GEMMs (MFMA), bias, leaky-relu, add, norm ----------
__global__ __launch_bounds__(256) void k_fused(const u16* __restrict__ side,
                                               const u16* __restrict__ ego_in,
                                               u16* __restrict__ ego_out,
                                               float* __restrict__ out,
                                               const float* __restrict__ gw,
                                               const float* __restrict__ gb,
                                               const float* __restrict__ bw,
                                               const float* __restrict__ bb,
                                               int layer){
  int lane = threadIdx.x & 63;
  int wave = threadIdx.x >> 6;
  int rowbase = blockIdx.x * 64 + wave * 16;
  int m = lane & 15, quad = lane >> 4;

  const float* gwL = gw + layer * 4096;
  const float* bwL = bw + layer * 4096;

  union F8 { s8 v; u16 h[8]; };

  // A fragments (A[m=lane&15][k=quad*8+j]): side and ego*side, rows rowbase..+15
  F8 as0, as1, ae0, ae1, ap0, ap1;
  int arow = (rowbase + m) * 64 + quad * 8;
  as0.v = *(const s8*)(side + arow);
  as1.v = *(const s8*)(side + arow + 32);
  ae0.v = *(const s8*)(ego_in + arow);
  ae1.v = *(const s8*)(ego_in + arow + 32);
  #pragma unroll
  for (int j = 0; j < 8; j++){
    ap0.h[j] = f2bf(bf2f(ae0.h[j]) * bf2f(as0.h[j]));
    ap1.h[j] = f2bf(bf2f(ae1.h[j]) * bf2f(as1.h[j]));
  }

  // B fragments: B[k][n] = W[n][k]; lane supplies n = lane&15, k = kb*32+quad*8+j
  F8 bg[4][2], bww[4][2];
  #pragma unroll
  for (int t = 0; t < 4; t++){
    #pragma unroll
    for (int kb = 0; kb < 2; kb++){
      int widx = (t * 16 + m) * 64 + kb * 32 + quad * 8;
      #pragma unroll
      for (int j = 0; j < 8; j++){
        bg[t][kb].h[j]  = f2bf(gwL[widx + j]);
        bww[t][kb].h[j] = f2bf(bwL[widx + j]);
      }
    }
  }

  f4 ag[4], ab[4];
  #pragma unroll
  for (int t = 0; t < 4; t++){
    ag[t] = (f4){0.f, 0.f, 0.f, 0.f};
    ab[t] = (f4){0.f, 0.f, 0.f, 0.f};
  }

  #pragma unroll
  for (int t = 0; t < 4; t++){
    ag[t] = __builtin_amdgcn_mfma_f32_16x16x32_bf16(as0.v, bg[t][0].v, ag[t], 0, 0, 0);
    ag[t] = __builtin_amdgcn_mfma_f32_16x16x32_bf16(as1.v, bg[t][1].v, ag[t], 0, 0, 0);
    ab[t] = __builtin_amdgcn_mfma_f32_16x16x32_bf16(ap0.v, bww[t][0].v, ab[t], 0, 0, 0);
    ab[t] = __builtin_amdgcn_mfma_f32_16x16x32_bf16(ap1.v, bww[t][1].v, ab[t], 0, 0, 0);
  }

  // epilogue: bias + leaky_relu(0.01) + add
  float ev[4][4];
  #pragma unroll
  for (int t = 0; t < 4; t++){
    float gcb = gb[layer * 64 + t * 16 + m];
    float bib = bb[layer * 64 + t * 16 + m];
    #pragma unroll
    for (int r = 0; r < 4; r++){
      float x = ag[t][r] + gcb; x = (x > 0.f) ? x : 0.01f * x;
      float y = ab[t][r] + bib; y = (y > 0.f) ? y : 0.01f * y;
      ev[t][r] = x + y;
    }
  }

  // row L2 norms: lane holds (row=quad*4+r, col=t*16+m); reduce over m (lane bits 0-3)
  float inv[4];
  #pragma unroll
  for (int r = 0; r < 4; r++){
    float p = 0.f;
    #pragma unroll
    for (int t = 0; t < 4; t++) p += ev[t][r] * ev[t][r];
    p += __shfl_xor(p, 1);
    p += __shfl_xor(p, 2);
    p += __shfl_xor(p, 4);
    p += __shfl_xor(p, 8);
    inv[r] = 1.0f / fmaxf(sqrtf(p), 1e-12f);
  }

  #pragma unroll
  for (int t = 0; t < 4; t++){
    #pragma unroll
    for (int r = 0; r < 4; r++){
      int row = rowbase + quad * 4 + r;
      int col = t * 16 + m;
      ego_out[row * 64 + col] = f2bf(ev[t][r]);                 // un-normalized ego (bf16)
      out[row * 256 + (layer + 1) * 64 + col] = ev[t][r] * inv[r];  // fp32 output
    }
  }
}

extern "C" void kernel_launch(void* const* d_in, const int* in_sizes, int n_in,
                              void* d_out, int out_size, void* d_ws, size_t ws_size,
                              hipStream_t stream) {
  const int*   rows = (const int*)d_in[0];
  const int*   cols = (const int*)d_in[1];
  const float* vals = (const float*)d_in[2];
  const float* ue   = (const float*)d_in[3];
  const float* ie   = (const float*)d_in[4];
  const float* gw   = (const float*)d_in[5];
  const float* gb   = (const float*)d_in[6];
  const float* bw   = (const float*)d_in[7];
  const float* bb   = (const float*)d_in[8];
  float* out = (float*)d_out;

  char* ws = (char*)d_ws;
  u16*   ego    = (u16*)(ws + 0);                   // 51,200,000 B
  u16*   side   = (u16*)(ws + 51200000);            // 51,200,000 B
  uint2* edges  = (uint2*)(ws + 102400000);         // 102,400,000 B
  uint2* tmp    = (uint2*)(ws + 0);                 // 102,400,000 B — overlaps ego+side,
                                                    // dead before k_init runs
  int*   off    = (int*)(ws + 204800000);           // 1,600,004 B
  int*   cstart = (int*)(ws + 206400032);           // 1,568 B (NB+1)
  int*   ccursor= (int*)(ws + 206401632);           // 1,564 B
  int*   cnt_b  = (int*)(ws + 206403232);           // 1,564 B

  hipMemsetAsync(cnt_b, 0, NB * sizeof(int), stream);

  // hierarchical counting sort: coarse 391-bucket partition, then per-bucket CSR
  k_chist<<<1024, 256, 0, stream>>>(rows, cnt_b);
  k_cscan<<<1, 512, 0, stream>>>(cnt_b, cstart, ccursor, off);
  k_part<<<NNZ / 4096, 512, 0, stream>>>(rows, cols, vals, ccursor, tmp);
  k_fine<<<NB, 256, 0, stream>>>(cstart, tmp, off, edges);

  k_init<<<(NTOT * DD) / 256, 256, 0, stream>>>(ue, ie, ego, out);

  for (int l = 0; l < 3; l++){
    k_spmm<<<(NTOT * 64) / 256, 256, 0, stream>>>(off, edges, ego, side);
    k_fused<<<NTOT / 64, 256, 0, stream>>>(side, ego, ego, out,
                                           gw, gb, bw, bb, l);
  }
}